// Round 1
// baseline (55340.637 us; speedup 1.0000x reference)
//
#include <hip/hip_runtime.h>

#define N_NODES 50000
#define N_EDGES 800000
#define N_ITERS 7

// ---------------------------------------------------------------------------
// transpose: W is [R][K] row-major; T[k*R + j] = W[j*K + k]
__global__ __launch_bounds__(256) void k_transpose(const float* __restrict__ W,
                                                   float* __restrict__ T,
                                                   int R, int K) {
    int idx = blockIdx.x * 256 + threadIdx.x;
    if (idx >= R * K) return;
    int j = idx / K, k = idx - j * K;
    T[k * R + j] = W[idx];
}

// ---------------------------------------------------------------------------
// Edge MLP layers 1+2 fused. Thread per edge.
// L1: acc1[96] = relu(b1 + m @ W1^T), m = [h[src] | h[dst]] (256)
//     W1T is [256][96] so per k-chunk the 4x96 weight block is contiguous.
// L2: per runtime j2: dot96(acc1, W2 row j2) -> relu -> out2T[j2][e] (coalesced)
__global__ __launch_bounds__(256) void k_edge_l12(
    const float* __restrict__ h,
    const int* __restrict__ src_ids, const int* __restrict__ dst_ids,
    const float* __restrict__ W1T,   // [256][96]
    const float* __restrict__ b1,    // [96]
    const float* __restrict__ W2,    // [96][96]
    const float* __restrict__ b2,    // [96]
    float* __restrict__ out2T,       // [96][ec_stride]
    int chunk_off, int csize, int ec_stride)
{
    int e = blockIdx.x * 256 + threadIdx.x;
    if (e >= csize) return;
    int ge = chunk_off + e;
    int src = src_ids[ge];
    int dst = dst_ids[ge];

    float acc[96];
#pragma unroll
    for (int j = 0; j < 96; j++) acc[j] = b1[j];

    const float4* rows = (const float4*)(h + (size_t)src * 128);
#pragma unroll 1
    for (int c = 0; c < 32; c++) {
        float4 m = rows[c];
        const float* w = W1T + (4 * c) * 96;   // uniform address -> scalar/broadcast
#pragma unroll
        for (int j = 0; j < 96; j++)
            acc[j] += m.x * w[j] + m.y * w[96 + j] + m.z * w[192 + j] + m.w * w[288 + j];
    }
    const float4* rowd = (const float4*)(h + (size_t)dst * 128);
#pragma unroll 1
    for (int c = 0; c < 32; c++) {
        float4 m = rowd[c];
        const float* w = W1T + (128 + 4 * c) * 96;
#pragma unroll
        for (int j = 0; j < 96; j++)
            acc[j] += m.x * w[j] + m.y * w[96 + j] + m.z * w[192 + j] + m.w * w[288 + j];
    }
#pragma unroll
    for (int j = 0; j < 96; j++) acc[j] = fmaxf(acc[j], 0.f);

    // L2: scalar relay, 4-way partial sums (no fp reassociation needed)
#pragma unroll 1
    for (int j2 = 0; j2 < 96; j2++) {
        const float* w = W2 + j2 * 96;
        float s0 = 0.f, s1 = 0.f, s2 = 0.f, s3 = 0.f;
#pragma unroll
        for (int k = 0; k < 96; k += 4) {
            s0 += acc[k]     * w[k];
            s1 += acc[k + 1] * w[k + 1];
            s2 += acc[k + 2] * w[k + 2];
            s3 += acc[k + 3] * w[k + 3];
        }
        float v = s0 + s1 + s2 + s3 + b2[j2];
        out2T[(size_t)j2 * ec_stride + e] = fmaxf(v, 0.f);
    }
}

// ---------------------------------------------------------------------------
// Edge MLP layer 3 + scatter-add. Thread per edge.
__global__ __launch_bounds__(256) void k_edge_l3(
    const float* __restrict__ out2T,  // [96][ec_stride]
    const int* __restrict__ dst_ids,
    const float* __restrict__ W3,     // [128][96]
    const float* __restrict__ b3,     // [128]
    float* __restrict__ agg,          // [N][128]
    int chunk_off, int csize, int ec_stride)
{
    int e = blockIdx.x * 256 + threadIdx.x;
    if (e >= csize) return;
    int dst = dst_ids[chunk_off + e];

    float r2[96];
#pragma unroll
    for (int k = 0; k < 96; k++) r2[k] = out2T[(size_t)k * ec_stride + e];

    float* arow = agg + (size_t)dst * 128;
#pragma unroll 1
    for (int j3 = 0; j3 < 128; j3++) {
        const float* w = W3 + j3 * 96;
        float s0 = 0.f, s1 = 0.f, s2 = 0.f, s3 = 0.f;
#pragma unroll
        for (int k = 0; k < 96; k += 4) {
            s0 += r2[k]     * w[k];
            s1 += r2[k + 1] * w[k + 1];
            s2 += r2[k + 2] * w[k + 2];
            s3 += r2[k + 3] * w[k + 3];
        }
        atomicAdd(arow + j3, s0 + s1 + s2 + s3 + b3[j3]);
    }
}

// ---------------------------------------------------------------------------
// GRU cell, in-place h update. Block = 256 threads = 128 dims x 2 groups;
// each thread handles 8 nodes for its dim d. 3125 blocks x 16 nodes = 50000.
__global__ __launch_bounds__(256) void k_gru(
    const float* __restrict__ inp,    // [N][64]
    const float* __restrict__ agg,    // [N][128]
    float* __restrict__ h,            // [N][128] (in-place)
    const float* __restrict__ WihT,   // [192][384]
    const float* __restrict__ WhhT,   // [128][384]
    const float* __restrict__ b_ih,   // [384]
    const float* __restrict__ b_hh)   // [384]
{
    int d = threadIdx.x & 127;
    int g = threadIdx.x >> 7;
    int nbase = blockIdx.x * 16 + g * 8;

    float ir[8], iz[8], in_[8], hr[8], hz[8], hn[8], hold[8];
#pragma unroll
    for (int i = 0; i < 8; i++) { ir[i]=0.f; iz[i]=0.f; in_[i]=0.f; hr[i]=0.f; hz[i]=0.f; hn[i]=0.f; }

    // phase A1: x part = node_inputs, k = 0..63
#pragma unroll 1
    for (int k = 0; k < 64; k += 4) {
        float wr[4], wz[4], wn[4];
#pragma unroll
        for (int kk = 0; kk < 4; kk++) {
            const float* w = WihT + (size_t)(k + kk) * 384;
            wr[kk] = w[d]; wz[kk] = w[128 + d]; wn[kk] = w[256 + d];
        }
#pragma unroll
        for (int i = 0; i < 8; i++) {
            float4 x = *(const float4*)(inp + (size_t)(nbase + i) * 64 + k);
            ir[i]  += x.x*wr[0] + x.y*wr[1] + x.z*wr[2] + x.w*wr[3];
            iz[i]  += x.x*wz[0] + x.y*wz[1] + x.z*wz[2] + x.w*wz[3];
            in_[i] += x.x*wn[0] + x.y*wn[1] + x.z*wn[2] + x.w*wn[3];
        }
    }
    // phase A2: x part = agg, k = 0..127 -> WihT rows 64+k
#pragma unroll 1
    for (int k = 0; k < 128; k += 4) {
        float wr[4], wz[4], wn[4];
#pragma unroll
        for (int kk = 0; kk < 4; kk++) {
            const float* w = WihT + (size_t)(64 + k + kk) * 384;
            wr[kk] = w[d]; wz[kk] = w[128 + d]; wn[kk] = w[256 + d];
        }
#pragma unroll
        for (int i = 0; i < 8; i++) {
            float4 x = *(const float4*)(agg + (size_t)(nbase + i) * 128 + k);
            ir[i]  += x.x*wr[0] + x.y*wr[1] + x.z*wr[2] + x.w*wr[3];
            iz[i]  += x.x*wz[0] + x.y*wz[1] + x.z*wz[2] + x.w*wz[3];
            in_[i] += x.x*wn[0] + x.y*wn[1] + x.z*wn[2] + x.w*wn[3];
        }
    }
    // phase B: gh from h
#pragma unroll 1
    for (int k = 0; k < 128; k += 4) {
        float wr[4], wz[4], wn[4];
#pragma unroll
        for (int kk = 0; kk < 4; kk++) {
            const float* w = WhhT + (size_t)(k + kk) * 384;
            wr[kk] = w[d]; wz[kk] = w[128 + d]; wn[kk] = w[256 + d];
        }
#pragma unroll
        for (int i = 0; i < 8; i++) {
            float4 x = *(const float4*)(h + (size_t)(nbase + i) * 128 + k);
            hr[i] += x.x*wr[0] + x.y*wr[1] + x.z*wr[2] + x.w*wr[3];
            hz[i] += x.x*wz[0] + x.y*wz[1] + x.z*wz[2] + x.w*wz[3];
            hn[i] += x.x*wn[0] + x.y*wn[1] + x.z*wn[2] + x.w*wn[3];
        }
    }
#pragma unroll
    for (int i = 0; i < 8; i++) hold[i] = h[(size_t)(nbase + i) * 128 + d];

    __syncthreads();   // all h reads done before any in-place write

    float bir = b_ih[d], biz = b_ih[128 + d], bin = b_ih[256 + d];
    float bhr = b_hh[d], bhz = b_hh[128 + d], bhn = b_hh[256 + d];
#pragma unroll
    for (int i = 0; i < 8; i++) {
        float r = 1.f / (1.f + __expf(-(ir[i] + bir + hr[i] + bhr)));
        float z = 1.f / (1.f + __expf(-(iz[i] + biz + hz[i] + bhz)));
        float n = tanhf(in_[i] + bin + r * (hn[i] + bhn));
        h[(size_t)(nbase + i) * 128 + d] = (1.f - z) * n + z * hold[i];
    }
}

// ---------------------------------------------------------------------------
// Output projection: out[iter][n][o] = b_out[o] + h[n] . W_out[o]
// Block = 64 o-lanes x 4 node slots; each thread 8 nodes.
__global__ __launch_bounds__(256) void k_out(
    const float* __restrict__ h,
    const float* __restrict__ W_out,  // [64][128]
    const float* __restrict__ b_out,  // [64]
    float* __restrict__ out, int iter)
{
    int o = threadIdx.x & 63;
    int slot = threadIdx.x >> 6;
    int nbase = blockIdx.x * 32 + slot * 8;

    float acc[8];
    float bo = b_out[o];
#pragma unroll
    for (int i = 0; i < 8; i++) acc[i] = bo;

    const float4* wv = (const float4*)(W_out + (size_t)o * 128);
#pragma unroll 1
    for (int k = 0; k < 128; k += 4) {
        float4 w = wv[k >> 2];
#pragma unroll
        for (int i = 0; i < 8; i++) {
            int n = nbase + i;
            if (n < N_NODES) {
                float4 x = *(const float4*)(h + (size_t)n * 128 + k);
                acc[i] += x.x*w.x + x.y*w.y + x.z*w.z + x.w*w.w;
            }
        }
    }
    float* op = out + (size_t)iter * N_NODES * 64;
#pragma unroll
    for (int i = 0; i < 8; i++) {
        int n = nbase + i;
        if (n < N_NODES) op[(size_t)n * 64 + o] = acc[i];
    }
}

// ---------------------------------------------------------------------------
extern "C" void kernel_launch(void* const* d_in, const int* in_sizes, int n_in,
                              void* d_out, int out_size, void* d_ws, size_t ws_size,
                              hipStream_t stream)
{
    const float* inp   = (const float*)d_in[0];
    const int*   src   = (const int*)d_in[1];
    const int*   dst   = (const int*)d_in[2];
    const float* W1    = (const float*)d_in[3];
    const float* b1    = (const float*)d_in[4];
    const float* W2    = (const float*)d_in[5];
    const float* b2    = (const float*)d_in[6];
    const float* W3    = (const float*)d_in[7];
    const float* b3    = (const float*)d_in[8];
    const float* W_ih  = (const float*)d_in[9];
    const float* W_hh  = (const float*)d_in[10];
    const float* b_ih  = (const float*)d_in[11];
    const float* b_hh  = (const float*)d_in[12];
    const float* W_out = (const float*)d_in[13];
    const float* b_out = (const float*)d_in[14];
    float* out = (float*)d_out;

    char* ws = (char*)d_ws;
    size_t off = 0;
    auto alloc = [&](size_t bytes) -> void* {
        void* p = ws + off;
        off += (bytes + 255) & ~(size_t)255;
        return p;
    };
    float* h    = (float*)alloc((size_t)N_NODES * 128 * 4);
    float* agg  = (float*)alloc((size_t)N_NODES * 128 * 4);
    float* W1T  = (float*)alloc((size_t)96 * 256 * 4);
    float* WihT = (float*)alloc((size_t)384 * 192 * 4);
    float* WhhT = (float*)alloc((size_t)384 * 128 * 4);

    size_t remain = (ws_size > off) ? (ws_size - off) : 0;
    long long ec = (long long)(remain / (96 * 4));
    if (ec > 102400) ec = 102400;
    ec &= ~(long long)255;
    if (ec < 256) ec = 256;   // if ws is this small we cannot run anyway
    int EC = (int)ec;
    float* out2T = (float*)alloc((size_t)96 * EC * 4);

    hipMemsetAsync(h, 0, (size_t)N_NODES * 128 * 4, stream);
    k_transpose<<<(96 * 256 + 255) / 256, 256, 0, stream>>>(W1, W1T, 96, 256);
    k_transpose<<<(384 * 192 + 255) / 256, 256, 0, stream>>>(W_ih, WihT, 384, 192);
    k_transpose<<<(384 * 128 + 255) / 256, 256, 0, stream>>>(W_hh, WhhT, 384, 128);

    for (int it = 0; it < N_ITERS; ++it) {
        hipMemsetAsync(agg, 0, (size_t)N_NODES * 128 * 4, stream);
        for (int co = 0; co < N_EDGES; co += EC) {
            int cs = N_EDGES - co; if (cs > EC) cs = EC;
            int blocks = (cs + 255) / 256;
            k_edge_l12<<<blocks, 256, 0, stream>>>(h, src, dst, W1T, b1, W2, b2,
                                                   out2T, co, cs, EC);
            k_edge_l3<<<blocks, 256, 0, stream>>>(out2T, dst, W3, b3, agg, co, cs, EC);
        }
        k_gru<<<N_NODES / 16, 256, 0, stream>>>(inp, agg, h, WihT, WhhT, b_ih, b_hh);
        k_out<<<(N_NODES + 31) / 32, 256, 0, stream>>>(h, W_out, b_out, out, it);
    }
}

// Round 2
// 16185.043 us; speedup vs baseline: 3.4192x; 3.4192x over previous
//
#include <hip/hip_runtime.h>

#define N_NODES 50000
#define N_EDGES 800000
#define N_ITERS 7
#define NPAD 50048   // N_NODES padded to multiple of 64

// ---------------------------------------------------------------------------
// transpose: W is [R][K] row-major; T[k*R + j] = W[j*K + k]
__global__ __launch_bounds__(256) void k_transpose(const float* __restrict__ W,
                                                   float* __restrict__ T,
                                                   int R, int K) {
    int idx = blockIdx.x * 256 + threadIdx.x;
    if (idx >= R * K) return;
    int j = idx / K, k = idx - j * K;
    T[k * R + j] = W[idx];
}

// ---------------------------------------------------------------------------
// WcombT[k][g] = sum_j W_ih[g][64+j] * W3[j][k]   (k<96, g<384, j<128)
__global__ __launch_bounds__(256) void k_comb(const float* __restrict__ W_ih,
                                              const float* __restrict__ W3,
                                              float* __restrict__ WcombT) {
    int idx = blockIdx.x * 256 + threadIdx.x;
    if (idx >= 384 * 96) return;
    int g = idx / 96, k = idx - g * 96;
    float s = 0.f;
    for (int j = 0; j < 128; j++) s += W_ih[g * 192 + 64 + j] * W3[j * 96 + k];
    WcombT[k * 384 + g] = s;
}

// vb3[g] = sum_j W_ih[g][64+j] * b3[j]
__global__ __launch_bounds__(256) void k_vb3(const float* __restrict__ W_ih,
                                             const float* __restrict__ b3,
                                             float* __restrict__ vb3) {
    int g = blockIdx.x * 256 + threadIdx.x;
    if (g >= 384) return;
    float s = 0.f;
    for (int j = 0; j < 128; j++) s += W_ih[g * 192 + 64 + j] * b3[j];
    vb3[g] = s;
}

// ---------------------------------------------------------------------------
// CSR build (once; ids fixed across iterations)
__global__ __launch_bounds__(256) void k_hist(const int* __restrict__ dst,
                                              int* __restrict__ counts) {
    int e = blockIdx.x * 256 + threadIdx.x;
    if (e < N_EDGES) atomicAdd(&counts[dst[e]], 1);
}

__global__ __launch_bounds__(1024) void k_scan(const int* __restrict__ counts,
                                               int* __restrict__ row_off) {
    __shared__ int sh[1024];
    int t = threadIdx.x;
    const int STR = 49;  // 1024*49 >= 50000
    int base = t * STR;
    int s = 0;
    for (int i = 0; i < STR; i++) {
        int n = base + i;
        if (n < N_NODES) s += counts[n];
    }
    sh[t] = s;
    __syncthreads();
    for (int off = 1; off < 1024; off <<= 1) {
        int v = (t >= off) ? sh[t - off] : 0;
        __syncthreads();
        sh[t] += v;
        __syncthreads();
    }
    int run = (t == 0) ? 0 : sh[t - 1];
    for (int i = 0; i < STR; i++) {
        int n = base + i;
        if (n < N_NODES) { row_off[n] = run; run += counts[n]; }
    }
    if (t == 1023) row_off[N_NODES] = run;
}

__global__ __launch_bounds__(256) void k_permute(const int* __restrict__ src,
                                                 const int* __restrict__ dst,
                                                 const int* __restrict__ row_off,
                                                 int* __restrict__ cursor,
                                                 int* __restrict__ perm_src,
                                                 int* __restrict__ perm_dst) {
    int e = blockIdx.x * 256 + threadIdx.x;
    if (e >= N_EDGES) return;
    int d = dst[e];
    int pos = row_off[d] + atomicAdd(&cursor[d], 1);
    perm_src[pos] = src[e];
    perm_dst[pos] = d;
}

// ---------------------------------------------------------------------------
// Edge MLP layers 1+2 fused, sorted-edge order. Thread per edge position.
// Writes relu(L2) to msgT[96][ec_stride] (coalesced).
__global__ __launch_bounds__(256) void k_edge(
    const float* __restrict__ h,
    const int* __restrict__ perm_src, const int* __restrict__ perm_dst,
    const float* __restrict__ W1T,   // [256][96]
    const float* __restrict__ b1,    // [96]
    const float* __restrict__ W2,    // [96][96]
    const float* __restrict__ b2,    // [96]
    float* __restrict__ msgT,        // [96][ec_stride]
    int chunk_off, int csize, int ec_stride)
{
    int e = blockIdx.x * 256 + threadIdx.x;
    if (e >= csize) return;
    int ge = chunk_off + e;
    int src = perm_src[ge];
    int dst = perm_dst[ge];

    float acc[96];
#pragma unroll
    for (int j = 0; j < 96; j++) acc[j] = b1[j];

    const float4* rows = (const float4*)(h + (size_t)src * 128);
#pragma unroll 1
    for (int c = 0; c < 32; c++) {
        float4 m = rows[c];
        const float* w = W1T + (4 * c) * 96;
#pragma unroll
        for (int j = 0; j < 96; j++)
            acc[j] += m.x * w[j] + m.y * w[96 + j] + m.z * w[192 + j] + m.w * w[288 + j];
    }
    const float4* rowd = (const float4*)(h + (size_t)dst * 128);
#pragma unroll 1
    for (int c = 0; c < 32; c++) {
        float4 m = rowd[c];
        const float* w = W1T + (128 + 4 * c) * 96;
#pragma unroll
        for (int j = 0; j < 96; j++)
            acc[j] += m.x * w[j] + m.y * w[96 + j] + m.z * w[192 + j] + m.w * w[288 + j];
    }
#pragma unroll
    for (int j = 0; j < 96; j++) acc[j] = fmaxf(acc[j], 0.f);

#pragma unroll 1
    for (int j2 = 0; j2 < 96; j2++) {
        const float* w = W2 + j2 * 96;
        float s0 = 0.f, s1 = 0.f, s2 = 0.f, s3 = 0.f;
#pragma unroll
        for (int k = 0; k < 96; k += 4) {
            s0 += acc[k]     * w[k];
            s1 += acc[k + 1] * w[k + 1];
            s2 += acc[k + 2] * w[k + 2];
            s3 += acc[k + 3] * w[k + 3];
        }
        float v = s0 + s1 + s2 + s3 + b2[j2];
        msgT[(size_t)j2 * ec_stride + e] = fmaxf(v, 0.f);
    }
}

// ---------------------------------------------------------------------------
// Segmented sum of msgT over each node's CSR range (clipped to chunk).
// Non-atomic += is safe: chunks execute sequentially on the stream.
__global__ __launch_bounds__(256) void k_reduce(
    const float* __restrict__ msgT,   // [96][ec_stride]
    const int* __restrict__ row_off,
    float* __restrict__ r2aggT,       // [96][NPAD]
    int chunk_off, int csize, int ec_stride)
{
    int n = blockIdx.x * 256 + threadIdx.x;
    if (n >= N_NODES) return;
    int k = blockIdx.y;
    int s = row_off[n], e = row_off[n + 1];
    int lo = s > chunk_off ? s : chunk_off;
    int hi0 = chunk_off + csize;
    int hi = e < hi0 ? e : hi0;
    if (lo >= hi) return;
    const float* row = msgT + (size_t)k * ec_stride - chunk_off;
    float sum = 0.f;
    for (int p = lo; p < hi; p++) sum += row[p];
    r2aggT[(size_t)k * NPAD + n] += sum;
}

// ---------------------------------------------------------------------------
// GRU cell with folded W3: gi = WihT[0:64]·inp + WcombT·r2 + deg*vb3 + b_ih
// Block = 256 threads = 128 dims x 2 groups; 16 nodes/block.
__global__ __launch_bounds__(256) void k_gru2(
    const float* __restrict__ inp,     // [N][64]
    const float* __restrict__ r2aggT,  // [96][NPAD]
    const int* __restrict__ row_off,   // [N+1] (for degree)
    float* __restrict__ h,             // [N][128] in-place
    const float* __restrict__ WihT,    // [192][384] (rows 0..63 used)
    const float* __restrict__ WhhT,    // [128][384]
    const float* __restrict__ WcombT,  // [96][384]
    const float* __restrict__ vb3,     // [384]
    const float* __restrict__ b_ih,    // [384]
    const float* __restrict__ b_hh)    // [384]
{
    __shared__ float r2s[16 * 96];
    int t = threadIdx.x;
    int d = t & 127;
    int g = t >> 7;
    int nb16 = blockIdx.x * 16;
    int nbase = nb16 + g * 8;

    for (int idx = t; idx < 1536; idx += 256) {
        int k = idx >> 4, i = idx & 15;
        r2s[idx] = r2aggT[(size_t)k * NPAD + nb16 + i];
    }
    __syncthreads();

    float ir[8], iz[8], in_[8], hr[8], hz[8], hn[8], hold[8];
#pragma unroll
    for (int i = 0; i < 8; i++) { ir[i]=0.f; iz[i]=0.f; in_[i]=0.f; hr[i]=0.f; hz[i]=0.f; hn[i]=0.f; }

    // A1: node_inputs, k = 0..63
#pragma unroll 1
    for (int k = 0; k < 64; k += 4) {
        float wr[4], wz[4], wn[4];
#pragma unroll
        for (int kk = 0; kk < 4; kk++) {
            const float* w = WihT + (size_t)(k + kk) * 384;
            wr[kk] = w[d]; wz[kk] = w[128 + d]; wn[kk] = w[256 + d];
        }
#pragma unroll
        for (int i = 0; i < 8; i++) {
            float4 x = *(const float4*)(inp + (size_t)(nbase + i) * 64 + k);
            ir[i]  += x.x*wr[0] + x.y*wr[1] + x.z*wr[2] + x.w*wr[3];
            iz[i]  += x.x*wz[0] + x.y*wz[1] + x.z*wz[2] + x.w*wz[3];
            in_[i] += x.x*wn[0] + x.y*wn[1] + x.z*wn[2] + x.w*wn[3];
        }
    }
    // A2: r2 aggregate via WcombT, k = 0..95
#pragma unroll 1
    for (int k = 0; k < 96; k++) {
        float wr = WcombT[k * 384 + d];
        float wz = WcombT[k * 384 + 128 + d];
        float wn = WcombT[k * 384 + 256 + d];
        const float* rr = r2s + k * 16 + g * 8;
#pragma unroll
        for (int i = 0; i < 8; i++) {
            float x = rr[i];
            ir[i] += x * wr; iz[i] += x * wz; in_[i] += x * wn;
        }
    }
    // B: gh from h
#pragma unroll 1
    for (int k = 0; k < 128; k += 4) {
        float wr[4], wz[4], wn[4];
#pragma unroll
        for (int kk = 0; kk < 4; kk++) {
            const float* w = WhhT + (size_t)(k + kk) * 384;
            wr[kk] = w[d]; wz[kk] = w[128 + d]; wn[kk] = w[256 + d];
        }
#pragma unroll
        for (int i = 0; i < 8; i++) {
            float4 x = *(const float4*)(h + (size_t)(nbase + i) * 128 + k);
            hr[i] += x.x*wr[0] + x.y*wr[1] + x.z*wr[2] + x.w*wr[3];
            hz[i] += x.x*wz[0] + x.y*wz[1] + x.z*wz[2] + x.w*wz[3];
            hn[i] += x.x*wn[0] + x.y*wn[1] + x.z*wn[2] + x.w*wn[3];
        }
    }
#pragma unroll
    for (int i = 0; i < 8; i++) hold[i] = h[(size_t)(nbase + i) * 128 + d];

    __syncthreads();   // all h reads before any in-place write (intra-block)

    float bir = b_ih[d], biz = b_ih[128 + d], bin = b_ih[256 + d];
    float bhr = b_hh[d], bhz = b_hh[128 + d], bhn = b_hh[256 + d];
    float vr = vb3[d], vz = vb3[128 + d], vn = vb3[256 + d];
#pragma unroll
    for (int i = 0; i < 8; i++) {
        int n = nbase + i;
        float degf = (float)(row_off[n + 1] - row_off[n]);
        float r = 1.f / (1.f + __expf(-(ir[i] + bir + degf * vr + hr[i] + bhr)));
        float z = 1.f / (1.f + __expf(-(iz[i] + biz + degf * vz + hz[i] + bhz)));
        float nn = tanhf(in_[i] + bin + degf * vn + r * (hn[i] + bhn));
        h[(size_t)n * 128 + d] = (1.f - z) * nn + z * hold[i];
    }
}

// ---------------------------------------------------------------------------
__global__ __launch_bounds__(256) void k_out(
    const float* __restrict__ h,
    const float* __restrict__ W_out,  // [64][128]
    const float* __restrict__ b_out,  // [64]
    float* __restrict__ out, int iter)
{
    int o = threadIdx.x & 63;
    int slot = threadIdx.x >> 6;
    int nbase = blockIdx.x * 32 + slot * 8;

    float acc[8];
    float bo = b_out[o];
#pragma unroll
    for (int i = 0; i < 8; i++) acc[i] = bo;

    const float4* wv = (const float4*)(W_out + (size_t)o * 128);
#pragma unroll 1
    for (int k = 0; k < 128; k += 4) {
        float4 w = wv[k >> 2];
#pragma unroll
        for (int i = 0; i < 8; i++) {
            int n = nbase + i;
            if (n < N_NODES) {
                float4 x = *(const float4*)(h + (size_t)n * 128 + k);
                acc[i] += x.x*w.x + x.y*w.y + x.z*w.z + x.w*w.w;
            }
        }
    }
    float* op = out + (size_t)iter * N_NODES * 64;
#pragma unroll
    for (int i = 0; i < 8; i++) {
        int n = nbase + i;
        if (n < N_NODES) op[(size_t)n * 64 + o] = acc[i];
    }
}

// ---------------------------------------------------------------------------
extern "C" void kernel_launch(void* const* d_in, const int* in_sizes, int n_in,
                              void* d_out, int out_size, void* d_ws, size_t ws_size,
                              hipStream_t stream)
{
    const float* inp   = (const float*)d_in[0];
    const int*   src   = (const int*)d_in[1];
    const int*   dst   = (const int*)d_in[2];
    const float* W1    = (const float*)d_in[3];
    const float* b1    = (const float*)d_in[4];
    const float* W2    = (const float*)d_in[5];
    const float* b2    = (const float*)d_in[6];
    const float* W3    = (const float*)d_in[7];
    const float* b3    = (const float*)d_in[8];
    const float* W_ih  = (const float*)d_in[9];
    const float* W_hh  = (const float*)d_in[10];
    const float* b_ih  = (const float*)d_in[11];
    const float* b_hh  = (const float*)d_in[12];
    const float* W_out = (const float*)d_in[13];
    const float* b_out = (const float*)d_in[14];
    float* out = (float*)d_out;

    char* ws = (char*)d_ws;
    size_t off = 0;
    auto alloc = [&](size_t bytes) -> void* {
        void* p = ws + off;
        off += (bytes + 255) & ~(size_t)255;
        return p;
    };
    float* h       = (float*)alloc((size_t)N_NODES * 128 * 4);
    float* r2aggT  = (float*)alloc((size_t)96 * NPAD * 4);
    float* W1T     = (float*)alloc((size_t)96 * 256 * 4);
    float* WihT    = (float*)alloc((size_t)384 * 192 * 4);
    float* WhhT    = (float*)alloc((size_t)384 * 128 * 4);
    float* WcombT  = (float*)alloc((size_t)96 * 384 * 4);
    float* vb3     = (float*)alloc((size_t)384 * 4);
    int*   counts  = (int*)alloc((size_t)N_NODES * 4);
    int*   cursor  = (int*)alloc((size_t)N_NODES * 4);
    int*   row_off = (int*)alloc((size_t)(N_NODES + 1) * 4);
    int*   perm_src= (int*)alloc((size_t)N_EDGES * 4);
    int*   perm_dst= (int*)alloc((size_t)N_EDGES * 4);

    size_t remain = (ws_size > off) ? (ws_size - off) : 0;
    long long ec = (long long)(remain / (96 * 4));
    if (ec > 102400) ec = 102400;
    ec &= ~(long long)255;
    if (ec < 256) ec = 256;
    int EC = (int)ec;
    float* msgT = (float*)alloc((size_t)96 * EC * 4);

    // ---- one-time preprocessing (runs every call; all on stream) ----
    hipMemsetAsync(h, 0, (size_t)N_NODES * 128 * 4, stream);
    hipMemsetAsync(counts, 0, (size_t)N_NODES * 4, stream);
    hipMemsetAsync(cursor, 0, (size_t)N_NODES * 4, stream);

    k_transpose<<<(96 * 256 + 255) / 256, 256, 0, stream>>>(W1, W1T, 96, 256);
    k_transpose<<<(384 * 192 + 255) / 256, 256, 0, stream>>>(W_ih, WihT, 384, 192);
    k_transpose<<<(384 * 128 + 255) / 256, 256, 0, stream>>>(W_hh, WhhT, 384, 128);
    k_comb<<<(384 * 96 + 255) / 256, 256, 0, stream>>>(W_ih, W3, WcombT);
    k_vb3<<<2, 256, 0, stream>>>(W_ih, b3, vb3);

    k_hist<<<(N_EDGES + 255) / 256, 256, 0, stream>>>(dst, counts);
    k_scan<<<1, 1024, 0, stream>>>(counts, row_off);
    k_permute<<<(N_EDGES + 255) / 256, 256, 0, stream>>>(src, dst, row_off, cursor,
                                                         perm_src, perm_dst);

    // ---- iterations ----
    dim3 rgrid((N_NODES + 255) / 256, 96);
    for (int it = 0; it < N_ITERS; ++it) {
        hipMemsetAsync(r2aggT, 0, (size_t)96 * NPAD * 4, stream);
        for (int co = 0; co < N_EDGES; co += EC) {
            int cs = N_EDGES - co; if (cs > EC) cs = EC;
            int blocks = (cs + 255) / 256;
            k_edge<<<blocks, 256, 0, stream>>>(h, perm_src, perm_dst, W1T, b1, W2, b2,
                                               msgT, co, cs, EC);
            k_reduce<<<rgrid, 256, 0, stream>>>(msgT, row_off, r2aggT, co, cs, EC);
        }
        k_gru2<<<N_NODES / 16, 256, 0, stream>>>(inp, r2aggT, row_off, h,
                                                 WihT, WhhT, WcombT, vb3, b_ih, b_hh);
        k_out<<<(N_NODES + 31) / 32, 256, 0, stream>>>(h, W_out, b_out, out, it);
    }
}

// Round 3
// 5956.215 us; speedup vs baseline: 9.2912x; 2.7173x over previous
//
#include <hip/hip_runtime.h>

#define N_NODES 50000
#define N_EDGES 800000
#define N_ITERS 7
#define NPAD 50048   // N_NODES padded to multiple of 64

typedef __attribute__((ext_vector_type(8))) short short8;
typedef __attribute__((ext_vector_type(4))) float f32x4;

#define MROW 264   // m_lds row: 256 bf16 + 8 pad (528 B, 16B-aligned, conflict-free b128)
#define AROW 104   // a1_lds row: 96 bf16 + 8 pad (208 B)

static __device__ __forceinline__ unsigned short f2bf(float f) {
    unsigned int u = __float_as_uint(f);
    unsigned int r = (u + 0x7fffu + ((u >> 16) & 1u)) >> 16;
    return (unsigned short)r;
}

// ---------------------------------------------------------------------------
// transpose: W is [R][K] row-major; T[k*R + j] = W[j*K + k]
__global__ __launch_bounds__(256) void k_transpose(const float* __restrict__ W,
                                                   float* __restrict__ T,
                                                   int R, int K) {
    int idx = blockIdx.x * 256 + threadIdx.x;
    if (idx >= R * K) return;
    int j = idx / K, k = idx - j * K;
    T[k * R + j] = W[idx];
}

// ---------------------------------------------------------------------------
// WcombT[k][g] = sum_j W_ih[g][64+j] * W3[j][k]   (k<96, g<384, j<128)
__global__ __launch_bounds__(256) void k_comb(const float* __restrict__ W_ih,
                                              const float* __restrict__ W3,
                                              float* __restrict__ WcombT) {
    int idx = blockIdx.x * 256 + threadIdx.x;
    if (idx >= 384 * 96) return;
    int g = idx / 96, k = idx - g * 96;
    float s = 0.f;
    for (int j = 0; j < 128; j++) s += W_ih[g * 192 + 64 + j] * W3[j * 96 + k];
    WcombT[k * 384 + g] = s;
}

// vb3[g] = sum_j W_ih[g][64+j] * b3[j]
__global__ __launch_bounds__(256) void k_vb3(const float* __restrict__ W_ih,
                                             const float* __restrict__ b3,
                                             float* __restrict__ vb3) {
    int g = blockIdx.x * 256 + threadIdx.x;
    if (g >= 384) return;
    float s = 0.f;
    for (int j = 0; j < 128; j++) s += W_ih[g * 192 + 64 + j] * b3[j];
    vb3[g] = s;
}

// ---------------------------------------------------------------------------
// Pack weight [96][K] fp32 -> bf16 MFMA A-fragments [6][KT][64][8]
// lane l of tile (mt,kt): row j = mt*16 + (l&15), k = kt*32 + (l>>4)*8 + jj
__global__ __launch_bounds__(256) void k_pack(const float* __restrict__ W,
                                              unsigned short* __restrict__ out,
                                              int K, int KT) {
    int idx = blockIdx.x * 256 + threadIdx.x;
    int total = 6 * KT * 512;
    if (idx >= total) return;
    int jj = idx & 7;
    int l  = (idx >> 3) & 63;
    int tile = idx >> 9;          // mt*KT + kt
    int kt = tile % KT;
    int mt = tile / KT;
    int j = mt * 16 + (l & 15);
    int k = kt * 32 + (l >> 4) * 8 + jj;
    out[idx] = f2bf(W[j * K + k]);
}

// ---------------------------------------------------------------------------
// h fp32 -> bf16 (RNE), 4 elements/thread
__global__ __launch_bounds__(256) void k_h2bf(const float* __restrict__ h,
                                              unsigned short* __restrict__ hbf) {
    int i4 = blockIdx.x * 256 + threadIdx.x;
    if (i4 >= N_NODES * 32) return;
    float4 v = ((const float4*)h)[i4];
    ushort4 o;
    o.x = f2bf(v.x); o.y = f2bf(v.y); o.z = f2bf(v.z); o.w = f2bf(v.w);
    ((ushort4*)hbf)[i4] = o;
}

// ---------------------------------------------------------------------------
// CSR build (once; ids fixed across iterations)
__global__ __launch_bounds__(256) void k_hist(const int* __restrict__ dst,
                                              int* __restrict__ counts) {
    int e = blockIdx.x * 256 + threadIdx.x;
    if (e < N_EDGES) atomicAdd(&counts[dst[e]], 1);
}

__global__ __launch_bounds__(1024) void k_scan(const int* __restrict__ counts,
                                               int* __restrict__ row_off) {
    __shared__ int sh[1024];
    int t = threadIdx.x;
    const int STR = 49;  // 1024*49 >= 50000
    int base = t * STR;
    int s = 0;
    for (int i = 0; i < STR; i++) {
        int n = base + i;
        if (n < N_NODES) s += counts[n];
    }
    sh[t] = s;
    __syncthreads();
    for (int off = 1; off < 1024; off <<= 1) {
        int v = (t >= off) ? sh[t - off] : 0;
        __syncthreads();
        sh[t] += v;
        __syncthreads();
    }
    int run = (t == 0) ? 0 : sh[t - 1];
    for (int i = 0; i < STR; i++) {
        int n = base + i;
        if (n < N_NODES) { row_off[n] = run; run += counts[n]; }
    }
    if (t == 1023) row_off[N_NODES] = run;
}

__global__ __launch_bounds__(256) void k_permute(const int* __restrict__ src,
                                                 const int* __restrict__ dst,
                                                 const int* __restrict__ row_off,
                                                 int* __restrict__ cursor,
                                                 int* __restrict__ perm_src,
                                                 int* __restrict__ perm_dst) {
    int e = blockIdx.x * 256 + threadIdx.x;
    if (e >= N_EDGES) return;
    int d = dst[e];
    int pos = row_off[d] + atomicAdd(&cursor[d], 1);
    perm_src[pos] = src[e];
    perm_dst[pos] = d;
}

// ---------------------------------------------------------------------------
// Edge MLP L1+L2 via bf16 MFMA, swapped operands (C = W * m^T).
// Block = 4 waves; each wave owns 16 edges. csize MUST be a multiple of 64.
__global__ __launch_bounds__(256) void k_edge_mfma(
    const unsigned short* __restrict__ hbf,   // [N][128] bf16
    const int* __restrict__ perm_src, const int* __restrict__ perm_dst,
    const short8* __restrict__ W1A,           // [6][8][64] frags
    const short8* __restrict__ W2A,           // [6][3][64] frags
    const float* __restrict__ b1,             // [96]
    const float* __restrict__ b2,             // [96]
    float* __restrict__ msgT,                 // [96][ec_stride]
    int chunk_off, int csize, int ec_stride)
{
    __shared__ __attribute__((aligned(16))) unsigned short m_lds[4][16][MROW];
    __shared__ __attribute__((aligned(16))) unsigned short a1_lds[4][16][AROW];
    int t = threadIdx.x;
    int w = t >> 6, l = t & 63;
    int ebase = blockIdx.x * 64 + w * 16;     // chunk-local

    // ---- stage gathered m rows: 8 x 16B per lane ----
#pragma unroll
    for (int i = 0; i < 8; i++) {
        int c = i * 64 + l;            // 0..511
        int e = c >> 5;                // edge slot 0..15
        int cc = c & 31;               // 16B chunk within 512B row
        int ge = chunk_off + ebase + e;
        int id = (cc < 16) ? perm_src[ge] : perm_dst[ge];
        short8 v = *(const short8*)(hbf + (size_t)id * 128 + (size_t)(cc & 15) * 8);
        *(short8*)(&m_lds[w][e][(cc & 15) * 8 + ((cc >> 4) << 7)]) = v;
    }
    __syncthreads();

    int col  = l & 15;   // edge (N-dim) for B and C; M-row selector for A
    int krow = l >> 4;   // 0..3

    // ---- L1: c1[mt] = W1[mt] * m^T ----
    f32x4 c1[6] = {};
#pragma unroll 2
    for (int kt = 0; kt < 8; kt++) {
        short8 b = *(const short8*)(&m_lds[w][col][kt * 32 + krow * 8]);
#pragma unroll
        for (int mt = 0; mt < 6; mt++) {
            short8 a = W1A[(mt * 8 + kt) * 64 + l];
            c1[mt] = __builtin_amdgcn_mfma_f32_16x16x32_bf16(a, b, c1[mt], 0, 0, 0);
        }
    }

    // ---- epilogue L1: bias + relu -> bf16 -> a1_lds[edge][j1] ----
#pragma unroll
    for (int mt = 0; mt < 6; mt++) {
#pragma unroll
        for (int r = 0; r < 4; r += 2) {
            int j0 = mt * 16 + krow * 4 + r;
            float v0 = fmaxf(c1[mt][r]     + b1[j0],     0.f);
            float v1 = fmaxf(c1[mt][r + 1] + b1[j0 + 1], 0.f);
            unsigned int p = (unsigned int)f2bf(v0) | ((unsigned int)f2bf(v1) << 16);
            *(unsigned int*)(&a1_lds[w][col][j0]) = p;
        }
    }
    __syncthreads();

    // ---- L2: c2[mt] = W2[mt] * a1^T ----
    f32x4 c2[6] = {};
#pragma unroll
    for (int kt = 0; kt < 3; kt++) {
        short8 b = *(const short8*)(&a1_lds[w][col][kt * 32 + krow * 8]);
#pragma unroll
        for (int mt = 0; mt < 6; mt++) {
            short8 a = W2A[(mt * 3 + kt) * 64 + l];
            c2[mt] = __builtin_amdgcn_mfma_f32_16x16x32_bf16(a, b, c2[mt], 0, 0, 0);
        }
    }

    // ---- epilogue L2: bias + relu -> msgT[j2][e] (coalesced across lanes) ----
    int eloc = ebase + col;
#pragma unroll
    for (int mt = 0; mt < 6; mt++) {
#pragma unroll
        for (int r = 0; r < 4; r++) {
            int j2 = mt * 16 + krow * 4 + r;
            msgT[(size_t)j2 * ec_stride + eloc] = fmaxf(c2[mt][r] + b2[j2], 0.f);
        }
    }
}

// ---------------------------------------------------------------------------
// Segmented sum of msgT over each node's CSR range (clipped to chunk).
__global__ __launch_bounds__(256) void k_reduce(
    const float* __restrict__ msgT,   // [96][ec_stride]
    const int* __restrict__ row_off,
    float* __restrict__ r2aggT,       // [96][NPAD]
    int chunk_off, int csize, int ec_stride)
{
    int n = blockIdx.x * 256 + threadIdx.x;
    if (n >= N_NODES) return;
    int k = blockIdx.y;
    int s = row_off[n], e = row_off[n + 1];
    int lo = s > chunk_off ? s : chunk_off;
    int hi0 = chunk_off + csize;
    int hi = e < hi0 ? e : hi0;
    if (lo >= hi) return;
    const float* row = msgT + (size_t)k * ec_stride - chunk_off;
    float sum = 0.f;
    for (int p = lo; p < hi; p++) sum += row[p];
    r2aggT[(size_t)k * NPAD + n] += sum;
}

// ---------------------------------------------------------------------------
// GRU cell with folded W3.
__global__ __launch_bounds__(256) void k_gru2(
    const float* __restrict__ inp,     // [N][64]
    const float* __restrict__ r2aggT,  // [96][NPAD]
    const int* __restrict__ row_off,   // [N+1] (degree)
    float* __restrict__ h,             // [N][128] in-place
    const float* __restrict__ WihT,    // [192][384]
    const float* __restrict__ WhhT,    // [128][384]
    const float* __restrict__ WcombT,  // [96][384]
    const float* __restrict__ vb3,     // [384]
    const float* __restrict__ b_ih,    // [384]
    const float* __restrict__ b_hh)    // [384]
{
    __shared__ float r2s[16 * 96];
    int t = threadIdx.x;
    int d = t & 127;
    int g = t >> 7;
    int nb16 = blockIdx.x * 16;
    int nbase = nb16 + g * 8;

    for (int idx = t; idx < 1536; idx += 256) {
        int k = idx >> 4, i = idx & 15;
        r2s[idx] = r2aggT[(size_t)k * NPAD + nb16 + i];
    }
    __syncthreads();

    float ir[8], iz[8], in_[8], hr[8], hz[8], hn[8], hold[8];
#pragma unroll
    for (int i = 0; i < 8; i++) { ir[i]=0.f; iz[i]=0.f; in_[i]=0.f; hr[i]=0.f; hz[i]=0.f; hn[i]=0.f; }

#pragma unroll 1
    for (int k = 0; k < 64; k += 4) {
        float wr[4], wz[4], wn[4];
#pragma unroll
        for (int kk = 0; kk < 4; kk++) {
            const float* w = WihT + (size_t)(k + kk) * 384;
            wr[kk] = w[d]; wz[kk] = w[128 + d]; wn[kk] = w[256 + d];
        }
#pragma unroll
        for (int i = 0; i < 8; i++) {
            float4 x = *(const float4*)(inp + (size_t)(nbase + i) * 64 + k);
            ir[i]  += x.x*wr[0] + x.y*wr[1] + x.z*wr[2] + x.w*wr[3];
            iz[i]  += x.x*wz[0] + x.y*wz[1] + x.z*wz[2] + x.w*wz[3];
            in_[i] += x.x*wn[0] + x.y*wn[1] + x.z*wn[2] + x.w*wn[3];
        }
    }
#pragma unroll 1
    for (int k = 0; k < 96; k++) {
        float wr = WcombT[k * 384 + d];
        float wz = WcombT[k * 384 + 128 + d];
        float wn = WcombT[k * 384 + 256 + d];
        const float* rr = r2s + k * 16 + g * 8;
#pragma unroll
        for (int i = 0; i < 8; i++) {
            float x = rr[i];
            ir[i] += x * wr; iz[i] += x * wz; in_[i] += x * wn;
        }
    }
#pragma unroll 1
    for (int k = 0; k < 128; k += 4) {
        float wr[4], wz[4], wn[4];
#pragma unroll
        for (int kk = 0; kk < 4; kk++) {
            const float* w = WhhT + (size_t)(k + kk) * 384;
            wr[kk] = w[d]; wz[kk] = w[128 + d]; wn[kk] = w[256 + d];
        }
#pragma unroll
        for (int i = 0; i < 8; i++) {
            float4 x = *(const float4*)(h + (size_t)(nbase + i) * 128 + k);
            hr[i] += x.x*wr[0] + x.y*wr[1] + x.z*wr[2] + x.w*wr[3];
            hz[i] += x.x*wz[0] + x.y*wz[1] + x.z*wz[2] + x.w*wz[3];
            hn[i] += x.x*wn[0] + x.y*wn[1] + x.z*wn[2] + x.w*wn[3];
        }
    }
#pragma unroll
    for (int i = 0; i < 8; i++) hold[i] = h[(size_t)(nbase + i) * 128 + d];

    __syncthreads();

    float bir = b_ih[d], biz = b_ih[128 + d], bin = b_ih[256 + d];
    float bhr = b_hh[d], bhz = b_hh[128 + d], bhn = b_hh[256 + d];
    float vr = vb3[d], vz = vb3[128 + d], vn = vb3[256 + d];
#pragma unroll
    for (int i = 0; i < 8; i++) {
        int n = nbase + i;
        float degf = (float)(row_off[n + 1] - row_off[n]);
        float r = 1.f / (1.f + __expf(-(ir[i] + bir + degf * vr + hr[i] + bhr)));
        float z = 1.f / (1.f + __expf(-(iz[i] + biz + degf * vz + hz[i] + bhz)));
        float nn = tanhf(in_[i] + bin + degf * vn + r * (hn[i] + bhn));
        h[(size_t)n * 128 + d] = (1.f - z) * nn + z * hold[i];
    }
}

// ---------------------------------------------------------------------------
__global__ __launch_bounds__(256) void k_out(
    const float* __restrict__ h,
    const float* __restrict__ W_out,  // [64][128]
    const float* __restrict__ b_out,  // [64]
    float* __restrict__ out, int iter)
{
    int o = threadIdx.x & 63;
    int slot = threadIdx.x >> 6;
    int nbase = blockIdx.x * 32 + slot * 8;

    float acc[8];
    float bo = b_out[o];
#pragma unroll
    for (int i = 0; i < 8; i++) acc[i] = bo;

    const float4* wv = (const float4*)(W_out + (size_t)o * 128);
#pragma unroll 1
    for (int k = 0; k < 128; k += 4) {
        float4 w = wv[k >> 2];
#pragma unroll
        for (int i = 0; i < 8; i++) {
            int n = nbase + i;
            if (n < N_NODES) {
                float4 x = *(const float4*)(h + (size_t)n * 128 + k);
                acc[i] += x.x*w.x + x.y*w.y + x.z*w.z + x.w*w.w;
            }
        }
    }
    float* op = out + (size_t)iter * N_NODES * 64;
#pragma unroll
    for (int i = 0; i < 8; i++) {
        int n = nbase + i;
        if (n < N_NODES) op[(size_t)n * 64 + o] = acc[i];
    }
}

// ---------------------------------------------------------------------------
extern "C" void kernel_launch(void* const* d_in, const int* in_sizes, int n_in,
                              void* d_out, int out_size, void* d_ws, size_t ws_size,
                              hipStream_t stream)
{
    const float* inp   = (const float*)d_in[0];
    const int*   src   = (const int*)d_in[1];
    const int*   dst   = (const int*)d_in[2];
    const float* W1    = (const float*)d_in[3];
    const float* b1    = (const float*)d_in[4];
    const float* W2    = (const float*)d_in[5];
    const float* b2    = (const float*)d_in[6];
    const float* W3    = (const float*)d_in[7];
    const float* b3    = (const float*)d_in[8];
    const float* W_ih  = (const float*)d_in[9];
    const float* W_hh  = (const float*)d_in[10];
    const float* b_ih  = (const float*)d_in[11];
    const float* b_hh  = (const float*)d_in[12];
    const float* W_out = (const float*)d_in[13];
    const float* b_out = (const float*)d_in[14];
    float* out = (float*)d_out;

    char* ws = (char*)d_ws;
    size_t off = 0;
    auto alloc = [&](size_t bytes) -> void* {
        void* p = ws + off;
        off += (bytes + 255) & ~(size_t)255;
        return p;
    };
    float* h       = (float*)alloc((size_t)N_NODES * 128 * 4);
    unsigned short* hbf = (unsigned short*)alloc((size_t)N_NODES * 128 * 2);
    float* r2aggT  = (float*)alloc((size_t)96 * NPAD * 4);
    float* WihT    = (float*)alloc((size_t)384 * 192 * 4);
    float* WhhT    = (float*)alloc((size_t)384 * 128 * 4);
    float* WcombT  = (float*)alloc((size_t)96 * 384 * 4);
    float* vb3     = (float*)alloc((size_t)384 * 4);
    unsigned short* W1A = (unsigned short*)alloc((size_t)6 * 8 * 64 * 8 * 2);
    unsigned short* W2A = (unsigned short*)alloc((size_t)6 * 3 * 64 * 8 * 2);
    int*   counts  = (int*)alloc((size_t)N_NODES * 4);
    int*   cursor  = (int*)alloc((size_t)N_NODES * 4);
    int*   row_off = (int*)alloc((size_t)(N_NODES + 1) * 4);
    int*   perm_src= (int*)alloc((size_t)N_EDGES * 4);
    int*   perm_dst= (int*)alloc((size_t)N_EDGES * 4);

    size_t remain = (ws_size > off) ? (ws_size - off) : 0;
    long long ec = (long long)(remain / (96 * 4));
    if (ec > 102400) ec = 102400;
    ec &= ~(long long)255;
    if (ec < 256) ec = 256;
    int EC = (int)ec;
    float* msgT = (float*)alloc((size_t)96 * EC * 4);

    // ---- one-time preprocessing ----
    hipMemsetAsync(h, 0, (size_t)N_NODES * 128 * 4, stream);
    hipMemsetAsync(counts, 0, (size_t)N_NODES * 4, stream);
    hipMemsetAsync(cursor, 0, (size_t)N_NODES * 4, stream);

    k_transpose<<<(384 * 192 + 255) / 256, 256, 0, stream>>>(W_ih, WihT, 384, 192);
    k_transpose<<<(384 * 128 + 255) / 256, 256, 0, stream>>>(W_hh, WhhT, 384, 128);
    k_comb<<<(384 * 96 + 255) / 256, 256, 0, stream>>>(W_ih, W3, WcombT);
    k_vb3<<<2, 256, 0, stream>>>(W_ih, b3, vb3);
    k_pack<<<(6 * 8 * 512 + 255) / 256, 256, 0, stream>>>(W1, W1A, 256, 8);
    k_pack<<<(6 * 3 * 512 + 255) / 256, 256, 0, stream>>>(W2, W2A, 96, 3);

    k_hist<<<(N_EDGES + 255) / 256, 256, 0, stream>>>(dst, counts);
    k_scan<<<1, 1024, 0, stream>>>(counts, row_off);
    k_permute<<<(N_EDGES + 255) / 256, 256, 0, stream>>>(src, dst, row_off, cursor,
                                                         perm_src, perm_dst);

    // ---- iterations ----
    dim3 rgrid((N_NODES + 255) / 256, 96);
    for (int it = 0; it < N_ITERS; ++it) {
        k_h2bf<<<(N_NODES * 32 + 255) / 256, 256, 0, stream>>>(h, hbf);
        hipMemsetAsync(r2aggT, 0, (size_t)96 * NPAD * 4, stream);
        for (int co = 0; co < N_EDGES; co += EC) {
            int cs = N_EDGES - co; if (cs > EC) cs = EC;
            // cs is always a multiple of 64 (EC mult of 256, N_EDGES mult of 64)
            k_edge_mfma<<<cs / 64, 256, 0, stream>>>(hbf, perm_src, perm_dst,
                                                     (const short8*)W1A, (const short8*)W2A,
                                                     b1, b2, msgT, co, cs, EC);
            k_reduce<<<rgrid, 256, 0, stream>>>(msgT, row_off, r2aggT, co, cs, EC);
        }
        k_gru2<<<N_NODES / 16, 256, 0, stream>>>(inp, r2aggT, row_off, h,
                                                 WihT, WhhT, WcombT, vb3, b_ih, b_hh);
        k_out<<<(N_NODES + 31) / 32, 256, 0, stream>>>(h, W_out, b_out, out, it);
    }
}

// Round 4
// 3122.101 us; speedup vs baseline: 17.7254x; 1.9078x over previous
//
#include <hip/hip_runtime.h>

#define N_NODES 50000
#define N_EDGES 800000
#define N_ITERS 7
#define NPAD 50048   // N_NODES padded (>= max nb+64 = 50048)

typedef __attribute__((ext_vector_type(8))) short short8;
typedef __attribute__((ext_vector_type(4))) float f32x4;

#define MROW 264   // m_lds row: 256 bf16 + 8 pad
#define AROW 104   // a1_lds row: 96 bf16 + 8 pad
#define XROW 296   // X row: 288 bf16 + 8 pad (592 B, 16B-aligned)

static __device__ __forceinline__ unsigned short f2bf(float f) {
    unsigned int u = __float_as_uint(f);
    unsigned int r = (u + 0x7fffu + ((u >> 16) & 1u)) >> 16;
    return (unsigned short)r;
}
static __device__ __forceinline__ float bf2f(unsigned short u) {
    return __uint_as_float(((unsigned int)u) << 16);
}

// ---------------------------------------------------------------------------
// Wbig [256][288]: rows = r,z gates; cols = [W_ih[:, :64] | W_ih[:,64:]@W3 | W_hh]
__global__ __launch_bounds__(256) void k_build_wbig(const float* __restrict__ W_ih,
                                                    const float* __restrict__ W3,
                                                    const float* __restrict__ W_hh,
                                                    float* __restrict__ Wbig) {
    int idx = blockIdx.x * 256 + threadIdx.x;
    if (idx >= 256 * 288) return;
    int g = idx / 288, k = idx - g * 288;
    float v;
    if (k < 64) v = W_ih[g * 192 + k];
    else if (k < 160) {
        int kk = k - 64; float s = 0.f;
        for (int j = 0; j < 128; j++) s += W_ih[g * 192 + 64 + j] * W3[j * 96 + kk];
        v = s;
    } else v = W_hh[g * 128 + (k - 160)];
    Wbig[idx] = v;
}

// Wni [128][160]: n-gate input part (W_ih rows 256..383, with W3 fold)
__global__ __launch_bounds__(256) void k_build_wni(const float* __restrict__ W_ih,
                                                   const float* __restrict__ W3,
                                                   float* __restrict__ Wni) {
    int idx = blockIdx.x * 256 + threadIdx.x;
    if (idx >= 128 * 160) return;
    int g = idx / 160, k = idx - g * 160;
    int gg = 256 + g;
    float v;
    if (k < 64) v = W_ih[gg * 192 + k];
    else {
        int kk = k - 64; float s = 0.f;
        for (int j = 0; j < 128; j++) s += W_ih[gg * 192 + 64 + j] * W3[j * 96 + kk];
        v = s;
    }
    Wni[idx] = v;
}

// vb3[g] = sum_j W_ih[g][64+j] * b3[j]
__global__ __launch_bounds__(256) void k_vb3(const float* __restrict__ W_ih,
                                             const float* __restrict__ b3,
                                             float* __restrict__ vb3) {
    int g = blockIdx.x * 256 + threadIdx.x;
    if (g >= 384) return;
    float s = 0.f;
    for (int j = 0; j < 128; j++) s += W_ih[g * 192 + 64 + j] * b3[j];
    vb3[g] = s;
}

// bsum[d] = b_ih[d] + (d<256 ? b_hh[d] : 0)
__global__ __launch_bounds__(256) void k_bsum(const float* __restrict__ b_ih,
                                              const float* __restrict__ b_hh,
                                              float* __restrict__ bsum) {
    int d = blockIdx.x * 256 + threadIdx.x;
    if (d >= 384) return;
    bsum[d] = b_ih[d] + (d < 256 ? b_hh[d] : 0.f);
}

// ---------------------------------------------------------------------------
// Generic pack: src fp32 (leading dim ld), element (row0+j, k) -> A-frags
// out layout [Mt][KT][64][8]; lane l: j = mt*16+(l&15), k = kt*32+(l>>4)*8+jj
__global__ __launch_bounds__(256) void k_pack2(const float* __restrict__ src,
                                               unsigned short* __restrict__ out,
                                               int Mt, int KT, int ld, int row0) {
    int idx = blockIdx.x * 256 + threadIdx.x;
    if (idx >= Mt * KT * 512) return;
    int jj = idx & 7;
    int l  = (idx >> 3) & 63;
    int tile = idx >> 9;
    int kt = tile % KT;
    int mt = tile / KT;
    int j = row0 + mt * 16 + (l & 15);
    int k = kt * 32 + (l >> 4) * 8 + jj;
    out[idx] = f2bf(src[(size_t)j * ld + k]);
}

// ---------------------------------------------------------------------------
// CSR build (once; ids fixed across iterations)
__global__ __launch_bounds__(256) void k_hist(const int* __restrict__ dst,
                                              int* __restrict__ counts) {
    int e = blockIdx.x * 256 + threadIdx.x;
    if (e < N_EDGES) atomicAdd(&counts[dst[e]], 1);
}

__global__ __launch_bounds__(1024) void k_scan(const int* __restrict__ counts,
                                               int* __restrict__ row_off) {
    __shared__ int sh[1024];
    int t = threadIdx.x;
    const int STR = 49;
    int base = t * STR;
    int s = 0;
    for (int i = 0; i < STR; i++) {
        int n = base + i;
        if (n < N_NODES) s += counts[n];
    }
    sh[t] = s;
    __syncthreads();
    for (int off = 1; off < 1024; off <<= 1) {
        int v = (t >= off) ? sh[t - off] : 0;
        __syncthreads();
        sh[t] += v;
        __syncthreads();
    }
    int run = (t == 0) ? 0 : sh[t - 1];
    for (int i = 0; i < STR; i++) {
        int n = base + i;
        if (n < N_NODES) { row_off[n] = run; run += counts[n]; }
    }
    if (t == 1023) row_off[N_NODES] = run;
}

__global__ __launch_bounds__(256) void k_permute(const int* __restrict__ src,
                                                 const int* __restrict__ dst,
                                                 const int* __restrict__ row_off,
                                                 int* __restrict__ cursor,
                                                 int* __restrict__ perm_src,
                                                 int* __restrict__ perm_dst) {
    int e = blockIdx.x * 256 + threadIdx.x;
    if (e >= N_EDGES) return;
    int d = dst[e];
    int pos = row_off[d] + atomicAdd(&cursor[d], 1);
    perm_src[pos] = src[e];
    perm_dst[pos] = d;
}

// ---------------------------------------------------------------------------
// Edge MLP L1+L2 via bf16 MFMA, swapped operands (C = W * m^T).
// Block = 4 waves; each wave owns 16 edges. csize multiple of 64.
__global__ __launch_bounds__(256) void k_edge_mfma(
    const unsigned short* __restrict__ hbf,   // [N][128] bf16
    const int* __restrict__ perm_src, const int* __restrict__ perm_dst,
    const short8* __restrict__ W1A,           // [6][8][64] frags
    const short8* __restrict__ W2A,           // [6][3][64] frags
    const float* __restrict__ b1,             // [96]
    const float* __restrict__ b2,             // [96]
    unsigned short* __restrict__ msgT,        // [96][ec_stride] bf16
    int chunk_off, int csize, int ec_stride)
{
    __shared__ __attribute__((aligned(16))) unsigned short m_lds[4][16][MROW];
    __shared__ __attribute__((aligned(16))) unsigned short a1_lds[4][16][AROW];
    int t = threadIdx.x;
    int w = t >> 6, l = t & 63;
    int ebase = blockIdx.x * 64 + w * 16;

#pragma unroll
    for (int i = 0; i < 8; i++) {
        int c = i * 64 + l;
        int e = c >> 5;
        int cc = c & 31;
        int ge = chunk_off + ebase + e;
        int id = (cc < 16) ? perm_src[ge] : perm_dst[ge];
        short8 v = *(const short8*)(hbf + (size_t)id * 128 + (size_t)(cc & 15) * 8);
        *(short8*)(&m_lds[w][e][(cc & 15) * 8 + ((cc >> 4) << 7)]) = v;
    }
    __syncthreads();

    int col  = l & 15;
    int krow = l >> 4;

    f32x4 c1[6] = {};
#pragma unroll 2
    for (int kt = 0; kt < 8; kt++) {
        short8 b = *(const short8*)(&m_lds[w][col][kt * 32 + krow * 8]);
#pragma unroll
        for (int mt = 0; mt < 6; mt++) {
            short8 a = W1A[(mt * 8 + kt) * 64 + l];
            c1[mt] = __builtin_amdgcn_mfma_f32_16x16x32_bf16(a, b, c1[mt], 0, 0, 0);
        }
    }

#pragma unroll
    for (int mt = 0; mt < 6; mt++) {
#pragma unroll
        for (int r = 0; r < 4; r += 2) {
            int j0 = mt * 16 + krow * 4 + r;
            float v0 = fmaxf(c1[mt][r]     + b1[j0],     0.f);
            float v1 = fmaxf(c1[mt][r + 1] + b1[j0 + 1], 0.f);
            unsigned int p = (unsigned int)f2bf(v0) | ((unsigned int)f2bf(v1) << 16);
            *(unsigned int*)(&a1_lds[w][col][j0]) = p;
        }
    }
    __syncthreads();

    f32x4 c2[6] = {};
#pragma unroll
    for (int kt = 0; kt < 3; kt++) {
        short8 b = *(const short8*)(&a1_lds[w][col][kt * 32 + krow * 8]);
#pragma unroll
        for (int mt = 0; mt < 6; mt++) {
            short8 a = W2A[(mt * 3 + kt) * 64 + l];
            c2[mt] = __builtin_amdgcn_mfma_f32_16x16x32_bf16(a, b, c2[mt], 0, 0, 0);
        }
    }

    int eloc = ebase + col;
#pragma unroll
    for (int mt = 0; mt < 6; mt++) {
#pragma unroll
        for (int r = 0; r < 4; r++) {
            int j2 = mt * 16 + krow * 4 + r;
            msgT[(size_t)j2 * ec_stride + eloc] = f2bf(fmaxf(c2[mt][r] + b2[j2], 0.f));
        }
    }
}

// ---------------------------------------------------------------------------
// Segmented sum of bf16 msgT over each node's CSR range (clipped to chunk).
__global__ __launch_bounds__(256) void k_reduce(
    const unsigned short* __restrict__ msgT,  // [96][ec_stride] bf16
    const int* __restrict__ row_off,
    float* __restrict__ r2aggT,               // [96][NPAD] fp32
    int chunk_off, int csize, int ec_stride)
{
    int n = blockIdx.x * 256 + threadIdx.x;
    if (n >= N_NODES) return;
    int k = blockIdx.y;
    int s = row_off[n], e = row_off[n + 1];
    int lo = s > chunk_off ? s : chunk_off;
    int hi0 = chunk_off + csize;
    int hi = e < hi0 ? e : hi0;
    if (lo >= hi) return;
    const unsigned short* row = msgT + (size_t)k * ec_stride - chunk_off;
    float sum = 0.f;
    for (int p = lo; p < hi; p++) sum += bf2f(row[p]);
    r2aggT[(size_t)k * NPAD + n] += sum;
}

// ---------------------------------------------------------------------------
// Node phase, all-MFMA: gates GEMMs + GRU elementwise + fused out-proj + hbf.
// Block = 4 waves x 16 nodes = 64 nodes.
__global__ __launch_bounds__(256) void k_node_mfma(
    const float* __restrict__ inp,      // [N][64]
    const float* __restrict__ r2aggT,   // [96][NPAD]
    const int* __restrict__ row_off,    // [N+1] (degree)
    float* __restrict__ h,              // [N][128] fp32 in/out
    unsigned short* __restrict__ hbf,   // [N][128] bf16 out
    const short8* __restrict__ WbigA,   // 16x9 frags (r,z | K=288)
    const short8* __restrict__ WniA,    // 8x5 frags (i_n | K=160)
    const short8* __restrict__ WnhA,    // 8x4 frags (h_n | K=128)
    const short8* __restrict__ WoutA,   // 4x4 frags (out | K=128)
    const float* __restrict__ vb3,      // [384]
    const float* __restrict__ bsum,     // [384]
    const float* __restrict__ b_hh,     // [384]
    const float* __restrict__ b_out,    // [64]
    float* __restrict__ out, int iter)
{
    __shared__ __attribute__((aligned(16))) unsigned short X[4][16][XROW];
    int t = threadIdx.x;
    int w = t >> 6, l = t & 63;
    int nb = blockIdx.x * 64;
    int col = l & 15, krow = l >> 4;

    // ---- stage X = [inp(64) | r2(96) | h(128)] as bf16 ----
    for (int idx = t; idx < 64 * 32; idx += 256) {      // inp pairs
        int i = idx >> 5, kk = (idx & 31) << 1;
        int n = nb + i;
        float2 v = make_float2(0.f, 0.f);
        if (n < N_NODES) v = *(const float2*)(inp + (size_t)n * 64 + kk);
        unsigned int p = (unsigned int)f2bf(v.x) | ((unsigned int)f2bf(v.y) << 16);
        *(unsigned int*)(&X[i >> 4][i & 15][kk]) = p;
    }
    for (int idx = t; idx < 96 * 64; idx += 256) {      // r2, k-major (zeros beyond N)
        int k = idx >> 6, i = idx & 63;
        float v = r2aggT[(size_t)k * NPAD + nb + i];
        X[i >> 4][i & 15][64 + k] = f2bf(v);
    }
    for (int idx = t; idx < 64 * 64; idx += 256) {      // h pairs
        int i = idx >> 6, kk = (idx & 63) << 1;
        int n = nb + i;
        float2 v = make_float2(0.f, 0.f);
        if (n < N_NODES) v = *(const float2*)(h + (size_t)n * 128 + kk);
        unsigned int p = (unsigned int)f2bf(v.x) | ((unsigned int)f2bf(v.y) << 16);
        *(unsigned int*)(&X[i >> 4][i & 15][160 + kk]) = p;
    }
    __syncthreads();

    // ---- gates r,z: [256 x 288] ----
    f32x4 cg[16] = {};
#pragma unroll 3
    for (int kt = 0; kt < 9; kt++) {
        short8 b = *(const short8*)(&X[w][col][kt * 32 + krow * 8]);
#pragma unroll
        for (int mt = 0; mt < 16; mt++)
            cg[mt] = __builtin_amdgcn_mfma_f32_16x16x32_bf16(WbigA[(mt * 9 + kt) * 64 + l], b, cg[mt], 0, 0, 0);
    }
    // ---- i_n: [128 x 160] ----
    f32x4 ci[8] = {};
#pragma unroll
    for (int kt = 0; kt < 5; kt++) {
        short8 b = *(const short8*)(&X[w][col][kt * 32 + krow * 8]);
#pragma unroll
        for (int mt = 0; mt < 8; mt++)
            ci[mt] = __builtin_amdgcn_mfma_f32_16x16x32_bf16(WniA[(mt * 5 + kt) * 64 + l], b, ci[mt], 0, 0, 0);
    }
    // ---- h_n: [128 x 128] ----
    f32x4 ch[8] = {};
#pragma unroll
    for (int kt = 0; kt < 4; kt++) {
        short8 b = *(const short8*)(&X[w][col][160 + kt * 32 + krow * 8]);
#pragma unroll
        for (int mt = 0; mt < 8; mt++)
            ch[mt] = __builtin_amdgcn_mfma_f32_16x16x32_bf16(WnhA[(mt * 4 + kt) * 64 + l], b, ch[mt], 0, 0, 0);
    }

    int n = nb + w * 16 + col;
    bool valid = (n < N_NODES);
    float deg = 0.f;
    if (valid) deg = (float)(row_off[n + 1] - row_off[n]);

    // ---- GRU epilogue: h_new fp32 -> global; bf16 -> LDS h-section ----
#pragma unroll
    for (int mt = 0; mt < 8; mt++) {
        float hv[4];
#pragma unroll
        for (int r = 0; r < 4; r++) {
            int d = mt * 16 + krow * 4 + r;
            float rp = cg[mt][r]     + bsum[d]       + deg * vb3[d];
            float zp = cg[mt + 8][r] + bsum[128 + d] + deg * vb3[128 + d];
            float ip = ci[mt][r]     + bsum[256 + d] + deg * vb3[256 + d];
            float hp = ch[mt][r]     + b_hh[256 + d];
            float rg = 1.f / (1.f + __expf(-rp));
            float zg = 1.f / (1.f + __expf(-zp));
            float ng = tanhf(ip + rg * hp);
            float ho = valid ? h[(size_t)n * 128 + d] : 0.f;
            hv[r] = (1.f - zg) * ng + zg * ho;
        }
        int d0 = mt * 16 + krow * 4;
        if (valid) {
            *(float2*)(h + (size_t)n * 128 + d0)     = make_float2(hv[0], hv[1]);
            *(float2*)(h + (size_t)n * 128 + d0 + 2) = make_float2(hv[2], hv[3]);
        }
        unsigned int p0 = (unsigned int)f2bf(hv[0]) | ((unsigned int)f2bf(hv[1]) << 16);
        unsigned int p1 = (unsigned int)f2bf(hv[2]) | ((unsigned int)f2bf(hv[3]) << 16);
        *(unsigned int*)(&X[w][col][160 + d0]) = p0;
        *(unsigned int*)(&X[w][col][160 + d0 + 2]) = p1;
    }
    __syncthreads();   // h_new bf16 visible to all lanes

    // ---- out projection: [64 x 128] on h_new ----
    f32x4 co[4] = {};
#pragma unroll
    for (int kt = 0; kt < 4; kt++) {
        short8 b = *(const short8*)(&X[w][col][160 + kt * 32 + krow * 8]);
#pragma unroll
        for (int mt = 0; mt < 4; mt++)
            co[mt] = __builtin_amdgcn_mfma_f32_16x16x32_bf16(WoutA[(mt * 4 + kt) * 64 + l], b, co[mt], 0, 0, 0);
    }
    if (valid) {
        float* op = out + (size_t)iter * N_NODES * 64 + (size_t)n * 64;
#pragma unroll
        for (int mt = 0; mt < 4; mt++) {
            int o0 = mt * 16 + krow * 4;
            *(float2*)(op + o0)     = make_float2(co[mt][0] + b_out[o0],     co[mt][1] + b_out[o0 + 1]);
            *(float2*)(op + o0 + 2) = make_float2(co[mt][2] + b_out[o0 + 2], co[mt][3] + b_out[o0 + 3]);
        }
    }

    // ---- coalesced hbf writeback ----
    for (int idx = t; idx < 64 * 32; idx += 256) {
        int i = idx >> 5, c = idx & 31;
        int n2 = nb + i;
        if (n2 < N_NODES)
            ((uint2*)(hbf + (size_t)n2 * 128))[c] = *(const uint2*)(&X[i >> 4][i & 15][160 + c * 4]);
    }
}

// ---------------------------------------------------------------------------
extern "C" void kernel_launch(void* const* d_in, const int* in_sizes, int n_in,
                              void* d_out, int out_size, void* d_ws, size_t ws_size,
                              hipStream_t stream)
{
    const float* inp   = (const float*)d_in[0];
    const int*   src   = (const int*)d_in[1];
    const int*   dst   = (const int*)d_in[2];
    const float* W1    = (const float*)d_in[3];
    const float* b1    = (const float*)d_in[4];
    const float* W2    = (const float*)d_in[5];
    const float* b2    = (const float*)d_in[6];
    const float* W3    = (const float*)d_in[7];
    const float* b3    = (const float*)d_in[8];
    const float* W_ih  = (const float*)d_in[9];
    const float* W_hh  = (const float*)d_in[10];
    const float* b_ih  = (const float*)d_in[11];
    const float* b_hh  = (const float*)d_in[12];
    const float* W_out = (const float*)d_in[13];
    const float* b_out = (const float*)d_in[14];
    float* out = (float*)d_out;

    char* ws = (char*)d_ws;
    size_t off = 0;
    auto alloc = [&](size_t bytes) -> void* {
        void* p = ws + off;
        off += (bytes + 255) & ~(size_t)255;
        return p;
    };
    float* h       = (float*)alloc((size_t)N_NODES * 128 * 4);
    unsigned short* hbf = (unsigned short*)alloc((size_t)N_NODES * 128 * 2);
    float* r2aggT  = (float*)alloc((size_t)96 * NPAD * 4);
    float* Wbig    = (float*)alloc((size_t)256 * 288 * 4);
    float* Wni     = (float*)alloc((size_t)128 * 160 * 4);
    float* vb3     = (float*)alloc((size_t)384 * 4);
    float* bsum    = (float*)alloc((size_t)384 * 4);
    unsigned short* W1A   = (unsigned short*)alloc((size_t)6 * 8 * 512 * 2);
    unsigned short* W2A   = (unsigned short*)alloc((size_t)6 * 3 * 512 * 2);
    unsigned short* WbigA = (unsigned short*)alloc((size_t)16 * 9 * 512 * 2);
    unsigned short* WniA  = (unsigned short*)alloc((size_t)8 * 5 * 512 * 2);
    unsigned short* WnhA  = (unsigned short*)alloc((size_t)8 * 4 * 512 * 2);
    unsigned short* WoutA = (unsigned short*)alloc((size_t)4 * 4 * 512 * 2);
    int*   counts  = (int*)alloc((size_t)N_NODES * 4);
    int*   cursor  = (int*)alloc((size_t)N_NODES * 4);
    int*   row_off = (int*)alloc((size_t)(N_NODES + 1) * 4);
    int*   perm_src= (int*)alloc((size_t)N_EDGES * 4);
    int*   perm_dst= (int*)alloc((size_t)N_EDGES * 4);

    size_t remain = (ws_size > off) ? (ws_size - off) : 0;
    long long ec = (long long)(remain / (96 * 2));
    if (ec > 204800) ec = 204800;
    ec &= ~(long long)255;
    if (ec < 256) ec = 256;
    int EC = (int)ec;
    unsigned short* msgT = (unsigned short*)alloc((size_t)96 * EC * 2);

    // ---- one-time preprocessing ----
    hipMemsetAsync(h, 0, (size_t)N_NODES * 128 * 4, stream);
    hipMemsetAsync(hbf, 0, (size_t)N_NODES * 128 * 2, stream);
    hipMemsetAsync(counts, 0, (size_t)N_NODES * 4, stream);
    hipMemsetAsync(cursor, 0, (size_t)N_NODES * 4, stream);

    k_build_wbig<<<(256 * 288 + 255) / 256, 256, 0, stream>>>(W_ih, W3, W_hh, Wbig);
    k_build_wni<<<(128 * 160 + 255) / 256, 256, 0, stream>>>(W_ih, W3, Wni);
    k_vb3<<<2, 256, 0, stream>>>(W_ih, b3, vb3);
    k_bsum<<<2, 256, 0, stream>>>(b_ih, b_hh, bsum);

    k_pack2<<<(6 * 8 * 512 + 255) / 256, 256, 0, stream>>>(W1, W1A, 6, 8, 256, 0);
    k_pack2<<<(6 * 3 * 512 + 255) / 256, 256, 0, stream>>>(W2, W2A, 6, 3, 96, 0);
    k_pack2<<<(16 * 9 * 512 + 255) / 256, 256, 0, stream>>>(Wbig, WbigA, 16, 9, 288, 0);
    k_pack2<<<(8 * 5 * 512 + 255) / 256, 256, 0, stream>>>(Wni, WniA, 8, 5, 160, 0);
    k_pack2<<<(8 * 4 * 512 + 255) / 256, 256, 0, stream>>>(W_hh, WnhA, 8, 4, 128, 256);
    k_pack2<<<(4 * 4 * 512 + 255) / 256, 256, 0, stream>>>(W_out, WoutA, 4, 4, 128, 0);

    k_hist<<<(N_EDGES + 255) / 256, 256, 0, stream>>>(dst, counts);
    k_scan<<<1, 1024, 0, stream>>>(counts, row_off);
    k_permute<<<(N_EDGES + 255) / 256, 256, 0, stream>>>(src, dst, row_off, cursor,
                                                         perm_src, perm_dst);

    // ---- iterations ----
    dim3 rgrid((N_NODES + 255) / 256, 96);
    int nblocks_node = (N_NODES + 63) / 64;
    for (int it = 0; it < N_ITERS; ++it) {
        hipMemsetAsync(r2aggT, 0, (size_t)96 * NPAD * 4, stream);
        for (int co = 0; co < N_EDGES; co += EC) {
            int cs = N_EDGES - co; if (cs > EC) cs = EC;
            k_edge_mfma<<<cs / 64, 256, 0, stream>>>(hbf, perm_src, perm_dst,
                                                     (const short8*)W1A, (const short8*)W2A,
                                                     b1, b2, msgT, co, cs, EC);
            k_reduce<<<rgrid, 256, 0, stream>>>(msgT, row_off, r2aggT, co, cs, EC);
        }
        k_node_mfma<<<nblocks_node, 256, 0, stream>>>(inp, r2aggT, row_off, h, hbf,
                                                      (const short8*)WbigA, (const short8*)WniA,
                                                      (const short8*)WnhA, (const short8*)WoutA,
                                                      vb3, bsum, b_hh, b_out, out, it);
    }
}